// Round 8
// baseline (604.504 us; speedup 1.0000x reference)
//
#include <hip/hip_runtime.h>
#include <stdint.h>

#define NE 50000   // entities
#define DD 128     // dim
#define RR 16      // relations
#define EE 50000   // edges per relation
#define NT 64      // node tile per block
#define NTOT (RR * NE)                 // 800000 flat (n,r) keys, node-major
#define SCAN_BLK 4096
#define NSCAN ((NTOT + SCAN_BLK - 1) / SCAN_BLK)   // 196

typedef short  shortx8 __attribute__((ext_vector_type(8)));
typedef short  shortx4 __attribute__((ext_vector_type(4)));
typedef float  floatx4 __attribute__((ext_vector_type(4)));

__device__ __forceinline__ unsigned short f2bf(float f) {
    unsigned u = __float_as_uint(f);
    u += 0x7fffu + ((u >> 16) & 1u);   // RNE
    return (unsigned short)(u >> 16);
}
__device__ __forceinline__ float bf2f(unsigned short h) {
    return __uint_as_float(((unsigned)h) << 16);
}

// ---- fused init: zero counts | rel_trans -> MFMA-fragment-ordered bf16 Tf |
//      ent_emb -> bf16 | zero Dacc0/Dacc1 (51.2MB)
// Tf: element T[r][row][k] at ((((r*8+(row>>4))*4+(k>>5))*64) + ((k>>3)&3)*16 + (row&15))*8 + (k&7)
#define ZB 782
#define TB 128
#define EB 6250
#define DZ 3125
__global__ void prep_k(const float* __restrict__ rt, unsigned short* __restrict__ Tf,
                       const float4* __restrict__ emb, shortx4* __restrict__ embA,
                       int* __restrict__ counts, int4* __restrict__ dzero) {
    int b = blockIdx.x, t = threadIdx.x;
    if (b < ZB) {
        int i4 = b * 256 + t;
        if (i4 < NTOT / 4) *(int4*)(counts + i4 * 4) = make_int4(0, 0, 0, 0);
    } else if (b < ZB + TB) {
        int c = (b - ZB) * 256 + t;          // chunk: 8 consecutive k of one (r,row)
        int r = c >> 11, row = (c >> 4) & 127, cb = c & 15;
        int kt = cb >> 2, qq = cb & 3, rg = row >> 4, m = row & 15;
        const float4* src = (const float4*)(rt + (size_t)c * 8);
        float4 v0 = src[0], v1 = src[1];
        shortx8 w;
        w[0] = (short)f2bf(v0.x); w[1] = (short)f2bf(v0.y);
        w[2] = (short)f2bf(v0.z); w[3] = (short)f2bf(v0.w);
        w[4] = (short)f2bf(v1.x); w[5] = (short)f2bf(v1.y);
        w[6] = (short)f2bf(v1.z); w[7] = (short)f2bf(v1.w);
        size_t idx = ((((size_t)r * 8 + rg) * 4 + kt) * 64 + qq * 16 + m) * 8;
        *(shortx8*)(Tf + idx) = w;
    } else if (b < ZB + TB + EB) {
        int i = (b - ZB - TB) * 256 + t;
        if (i < NE * DD / 4) {
            float4 v = emb[i];
            shortx4 w;
            w[0] = (short)f2bf(v.x); w[1] = (short)f2bf(v.y);
            w[2] = (short)f2bf(v.z); w[3] = (short)f2bf(v.w);
            embA[i] = w;
        }
    } else {
        // zero Dacc0+Dacc1: 2*NE*DD floats = 3.2M int4, 1024 int4/block
        size_t base = (size_t)(b - ZB - TB - EB) * 1024 + t;
        #pragma unroll
        for (int k = 0; k < 4; k++)
            dzero[base + k * 256] = make_int4(0, 0, 0, 0);
    }
}

// key = node*RR + r (node-major). Saves per-edge bucket rank so fill needs no atomics.
__global__ void hist_k(const int* __restrict__ erow, int* __restrict__ counts,
                       uchar4* __restrict__ rank) {
    int r  = blockIdx.y;
    int i4 = blockIdx.x * 256 + threadIdx.x;
    if (i4 < EE / 4) {
        int4 rw = *(const int4*)(erow + (size_t)r * EE + i4 * 4);
        uchar4 rk;
        rk.x = (unsigned char)atomicAdd(&counts[rw.x * RR + r], 1);
        rk.y = (unsigned char)atomicAdd(&counts[rw.y * RR + r], 1);
        rk.z = (unsigned char)atomicAdd(&counts[rw.z * RR + r], 1);
        rk.w = (unsigned char)atomicAdd(&counts[rw.w * RR + r], 1);
        rank[(size_t)r * (EE / 4) + i4] = rk;
    }
}

__global__ void scanA(const int* __restrict__ c, int* __restrict__ bsum) {
    int b = blockIdx.x, t = threadIdx.x;
    int base = b * SCAN_BLK + t * 16;
    int s = 0;
    #pragma unroll
    for (int i = 0; i < 16; i++) {
        int idx = base + i;
        if (idx < NTOT) s += c[idx];
    }
    __shared__ int sh[256];
    sh[t] = s;
    __syncthreads();
    for (int off = 128; off > 0; off >>= 1) {
        if (t < off) sh[t] += sh[t + off];
        __syncthreads();
    }
    if (t == 0) bsum[b] = sh[0];
}

// scanC derives its own block prefix from raw bsum (scanB folded in).
__global__ void scanC(const int* __restrict__ counts, int* __restrict__ rp,
                      const int* __restrict__ bsum) {
    int b = blockIdx.x, t = threadIdx.x;
    __shared__ int shb[256];
    shb[t] = (t < NSCAN) ? bsum[t] : 0;
    __syncthreads();
    for (int off = 1; off < 256; off <<= 1) {
        int add = (t >= off) ? shb[t - off] : 0;
        __syncthreads();
        shb[t] += add;
        __syncthreads();
    }
    int blockPrefix = (b > 0) ? shb[b - 1] : 0;
    int base = b * SCAN_BLK + t * 16;
    int vals[16];
    int s = 0;
    #pragma unroll
    for (int i = 0; i < 16; i++) {
        int idx = base + i;
        vals[i] = (idx < NTOT) ? counts[idx] : 0;
        s += vals[i];
    }
    __shared__ int sh[256];
    sh[t] = s;
    __syncthreads();
    for (int off = 1; off < 256; off <<= 1) {
        int add = (t >= off) ? sh[t - off] : 0;
        __syncthreads();
        sh[t] += add;
        __syncthreads();
    }
    int run = blockPrefix + sh[t] - s;
    #pragma unroll
    for (int i = 0; i < 16; i++) {
        int idx = base + i;
        if (idx < NTOT) {
            rp[idx] = run;
            run += vals[i];
            if (idx == NTOT - 1) rp[NTOT] = run;
        }
    }
}

// atomic-free placement: pos = rp[key] + saved rank
__global__ void fill_k(const int* __restrict__ erow, const int* __restrict__ ecol,
                       const float* __restrict__ eval, const int* __restrict__ rp,
                       const uchar4* __restrict__ rank, int2* __restrict__ edges) {
    int r  = blockIdx.y;
    int i4 = blockIdx.x * 256 + threadIdx.x;
    if (i4 < EE / 4) {
        int4   rw = *(const int4*)(erow + (size_t)r * EE + i4 * 4);
        int4   cl = *(const int4*)(ecol + (size_t)r * EE + i4 * 4);
        float4 vl = *(const float4*)(eval + (size_t)r * EE + i4 * 4);
        uchar4 rk = rank[(size_t)r * (EE / 4) + i4];
        edges[rp[rw.x * RR + r] + rk.x] = make_int2(cl.x, __float_as_int(vl.x));
        edges[rp[rw.y * RR + r] + rk.y] = make_int2(cl.y, __float_as_int(vl.y));
        edges[rp[rw.z * RR + r] + rk.z] = make_int2(cl.z, __float_as_int(vl.z));
        edges[rp[rw.w * RR + r] + rk.w] = make_int2(cl.w, __float_as_int(vl.w));
    }
}

__device__ __forceinline__ void accum_chunks(float a0[8], float a1[8], float v,
                                             shortx8 c0, shortx8 c1) {
    #pragma unroll
    for (int j = 0; j < 8; j++) {
        a0[j] = fmaf(v, bf2f((unsigned short)c0[j]), a0[j]);
        a1[j] = fmaf(v, bf2f((unsigned short)c1[j]), a1[j]);
    }
}
// f32 source (layer-2: reads Dacc0 partial sums, relu applied at read)
__device__ __forceinline__ void accum_f32(float a0[8], float a1[8], float v,
                                          const float* rowp) {
    floatx4 f0 = *(const floatx4*)(rowp);
    floatx4 f1 = *(const floatx4*)(rowp + 4);
    floatx4 f2 = *(const floatx4*)(rowp + 64);
    floatx4 f3 = *(const floatx4*)(rowp + 68);
    #pragma unroll
    for (int j = 0; j < 4; j++) {
        a0[j]     = fmaf(v, fmaxf(f0[j], 0.f), a0[j]);
        a0[4 + j] = fmaf(v, fmaxf(f1[j], 0.f), a0[4 + j]);
        a1[j]     = fmaf(v, fmaxf(f2[j], 0.f), a1[j]);
        a1[4 + j] = fmaf(v, fmaxf(f3[j], 0.f), a1[4 + j]);
    }
}

// Fused layer, RELATION-SPLIT: blockIdx.y in {0,1} -> this block handles 8
// relations (rbase..rbase+7) for its 64-node tile. Block-relations invariant
// (1564 x 8 = 12512, same as R0's 782 x 16) but streams/CU double -> the
// measured wall (serial relation chain / overlap) should ~halve. Inner loop
// byte-identical to R0 (the only structure that won). Halves combine via f32
// atomicAdd into Dacc (exactly 2 adds/address, a+b==b+a -> deterministic).
// SRCF: layer-2 gathers f32 partials from Dacc0 with relu at read (no bf16
// intermediate, no reduce kernel).
template<bool SRCF>
__global__ __launch_bounds__(256, 4)
void layer_k(const void* __restrict__ srcP,
             const unsigned short* __restrict__ Tf,
             const int* __restrict__ rp,
             const int2* __restrict__ eg,
             float* __restrict__ Dout)
{
    __shared__ __align__(16) unsigned short Bt[64 * 128];   // 16 KB

    const unsigned short* embIn = (const unsigned short*)srcP;  // bf16 path
    const float*          fIn   = (const float*)srcP;           // f32 path

    const int t     = threadIdx.x;
    const int lane  = t & 63;
    const int w     = t >> 6;      // 0..3: i block (x32)
    const int colq  = lane & 15;
    const int q     = lane >> 4;
    const int n0    = blockIdx.x * NT;
    const int rbase = blockIdx.y * 8;
    const int nsub  = t >> 3;      // node within pass (0..31)
    const int dgrp  = t & 7;       // dim chunks dgrp, dgrp+8

    floatx4 acc[2][4];
    #pragma unroll
    for (int a = 0; a < 2; a++)
        #pragma unroll
        for (int c = 0; c < 4; c++)
            acc[a][c] = (floatx4){0.f, 0.f, 0.f, 0.f};

    #pragma unroll 1
    for (int rr = 0; rr < 8; rr++) {
        const int r = rbase + rr;
        // ---- gather (branchless): meta, first 2 edges, 2 rows, FMA+pack -> Bt
        int s_[2], c_[2];
        #pragma unroll
        for (int p = 0; p < 2; p++) {
            int n = n0 + p * 32 + nsub;
            bool ok = n < NE;
            int key = (ok ? n : 0) * RR + r;
            int a = rp[key], b2 = rp[key + 1];
            s_[p] = a; c_[p] = ok ? (b2 - a) : 0;
        }
        int   col0[2], col1[2];
        float v0_[2], v1_[2];
        #pragma unroll
        for (int p = 0; p < 2; p++) {
            int2 E0 = eg[s_[p]];          // edges padded; discarded when c==0
            int2 E1 = eg[s_[p] + 1];
            col0[p] = c_[p] > 0 ? E0.x : 0;
            col1[p] = c_[p] > 1 ? E1.x : 0;
            v0_[p]  = c_[p] > 0 ? __int_as_float(E0.y) : 0.f;
            v1_[p]  = c_[p] > 1 ? __int_as_float(E1.y) : 0.f;
        }
        #pragma unroll
        for (int p = 0; p < 2; p++) {
            float a0[8], a1[8];
            #pragma unroll
            for (int j = 0; j < 8; j++) { a0[j] = 0.f; a1[j] = 0.f; }
            if constexpr (!SRCF) {
                const unsigned short* r0 = embIn + (size_t)col0[p] * DD + dgrp * 8;
                const unsigned short* r1 = embIn + (size_t)col1[p] * DD + dgrp * 8;
                shortx8 m00 = *(const shortx8*)r0;
                shortx8 m01 = *(const shortx8*)(r0 + 64);
                shortx8 m10 = *(const shortx8*)r1;
                shortx8 m11 = *(const shortx8*)(r1 + 64);
                accum_chunks(a0, a1, v0_[p], m00, m01);
                accum_chunks(a0, a1, v1_[p], m10, m11);
                if (c_[p] > 2) {
                    #pragma unroll 1
                    for (int k = s_[p] + 2; k < s_[p] + c_[p]; k++) {
                        int2 E = eg[k];
                        float v = __int_as_float(E.y);
                        const unsigned short* rw_ = embIn + (size_t)E.x * DD + dgrp * 8;
                        accum_chunks(a0, a1, v, *(const shortx8*)rw_, *(const shortx8*)(rw_ + 64));
                    }
                }
            } else {
                accum_f32(a0, a1, v0_[p], fIn + (size_t)col0[p] * DD + dgrp * 8);
                accum_f32(a0, a1, v1_[p], fIn + (size_t)col1[p] * DD + dgrp * 8);
                if (c_[p] > 2) {
                    #pragma unroll 1
                    for (int k = s_[p] + 2; k < s_[p] + c_[p]; k++) {
                        int2 E = eg[k];
                        float v = __int_as_float(E.y);
                        accum_f32(a0, a1, v, fIn + (size_t)E.x * DD + dgrp * 8);
                    }
                }
            }
            int nl = p * 32 + nsub;
            shortx8 w0, w1;
            #pragma unroll
            for (int j = 0; j < 8; j++) { w0[j] = (short)f2bf(a0[j]); w1[j] = (short)f2bf(a1[j]); }
            int pc = (dgrp ^ nl) & 7;
            *(shortx8*)&Bt[nl * 128 + pc * 8] = w0;
            *(shortx8*)&Bt[nl * 128 + (8 | pc) * 8] = w1;
        }
        __syncthreads();   // Bt(r) ready

        // ---- MFMA: A-frags from L2-resident Tf (1 kt prefetch), B from Bt
        shortx8 afN[2];
        #pragma unroll
        for (int it2 = 0; it2 < 2; it2++)
            afN[it2] = *(const shortx8*)(Tf + ((((size_t)r * 8 + (w * 2 + it2)) * 4 + 0) * 64 + lane) * 8);
        #pragma unroll 1
        for (int kt = 0; kt < 4; kt++) {
            shortx8 afC[2];
            afC[0] = afN[0]; afC[1] = afN[1];
            if (kt < 3) {
                #pragma unroll
                for (int it2 = 0; it2 < 2; it2++)
                    afN[it2] = *(const shortx8*)(Tf + ((((size_t)r * 8 + (w * 2 + it2)) * 4 + (kt + 1)) * 64 + lane) * 8);
            }
            int lc = kt * 4 + q;
            shortx8 bfr[4];
            #pragma unroll
            for (int c = 0; c < 4; c++) {
                int nl = c * 16 + colq;
                int pcr = (lc & 8) | ((lc ^ nl) & 7);
                bfr[c] = *(const shortx8*)&Bt[nl * 128 + pcr * 8];
            }
            #pragma unroll
            for (int it2 = 0; it2 < 2; it2++)
                #pragma unroll
                for (int c = 0; c < 4; c++)
                    acc[it2][c] = __builtin_amdgcn_mfma_f32_16x16x32_bf16(afC[it2], bfr[c], acc[it2][c], 0, 0, 0);
        }
        __syncthreads();   // MFMA done with Bt
    }

    // ---- epilogue: atomic f32 add of this half's partial into Dacc.
    // D: col=lane&15 -> n, row=q*4+g -> i (within 16x16 tile)
    #pragma unroll
    for (int c = 0; c < 4; c++) {
        int n = n0 + c * 16 + colq;
        if (n < NE) {
            #pragma unroll
            for (int it2 = 0; it2 < 2; it2++) {
                float* dst = Dout + ((size_t)n * DD + w * 32 + it2 * 16 + q * 4);
                #pragma unroll
                for (int g = 0; g < 4; g++)
                    atomicAdd(dst + g, acc[it2][c][g]);
            }
        }
    }
}

// relu + L2-normalize rows of Dacc1 -> out. 8 nodes/block, 32 lanes/node.
__global__ __launch_bounds__(256)
void final_k(const float* __restrict__ Dacc, float* __restrict__ out) {
    int t = threadIdx.x;
    int node = blockIdx.x * 8 + (t >> 5);
    int l = t & 31;
    floatx4 v = *(const floatx4*)(Dacc + (size_t)node * DD + l * 4);
    float ss = 0.f;
    #pragma unroll
    for (int g = 0; g < 4; g++) {
        v[g] = v[g] > 0.f ? v[g] : 0.f;
        ss += v[g] * v[g];
    }
    ss += __shfl_xor(ss, 1,  64);
    ss += __shfl_xor(ss, 2,  64);
    ss += __shfl_xor(ss, 4,  64);
    ss += __shfl_xor(ss, 8,  64);
    ss += __shfl_xor(ss, 16, 64);
    float scale = 1.f / fmaxf(sqrtf(ss), 1e-12f);
    floatx4 o;
    #pragma unroll
    for (int g = 0; g < 4; g++) o[g] = v[g] * scale;
    *(floatx4*)(out + (size_t)node * DD + l * 4) = o;
}

static inline size_t align256(size_t x) { return (x + 255) & ~(size_t)255; }

extern "C" void kernel_launch(void* const* d_in, const int* in_sizes, int n_in,
                              void* d_out, int out_size, void* d_ws, size_t ws_size,
                              hipStream_t stream)
{
    const float* ent_emb   = (const float*)d_in[0];   // [NE, DD] fp32
    const float* rel_trans = (const float*)d_in[1];   // [RR, DD, DD] fp32
    const float* edge_val  = (const float*)d_in[2];   // [RR, EE] fp32
    const int*   edge_row  = (const int*)d_in[3];     // [RR, EE] int32
    const int*   edge_col  = (const int*)d_in[4];     // [RR, EE] int32
    float* out = (float*)d_out;                       // [NE, DD] fp32

    char* ws = (char*)d_ws;
    size_t off = 0;
    int* counts = (int*)(ws + off);  off = align256(off + (size_t)NTOT * 4);
    int* rpf    = (int*)(ws + off);  off = align256(off + ((size_t)NTOT + 1) * 4);
    int* bsum   = (int*)(ws + off);  off = align256(off + 256 * 4);
    uchar4* rank = (uchar4*)(ws + off); off = align256(off + (size_t)NTOT);
    int2* edges = (int2*)(ws + off); off = align256(off + ((size_t)NTOT + 8) * 8);  // +pad for 2-edge overread
    unsigned short* Tf = (unsigned short*)(ws + off); off = align256(off + (size_t)RR * DD * DD * 2);
    unsigned short* embA = (unsigned short*)(ws + off); off = align256(off + (size_t)NE * DD * 2);
    float* Dacc0 = (float*)(ws + off); off = align256(off + (size_t)NE * DD * 4);
    float* Dacc1 = (float*)(ws + off); off = align256(off + (size_t)NE * DD * 4);
    // total ~79 MB (Dacc0/Dacc1 contiguous -> zeroed as one region in prep)

    prep_k<<<ZB + TB + EB + DZ, 256, 0, stream>>>(rel_trans, Tf, (const float4*)ent_emb,
                                                  (shortx4*)embA, counts, (int4*)Dacc0);
    dim3 eg_grid((EE / 4 + 255) / 256, RR);
    hist_k<<<eg_grid, 256, 0, stream>>>(edge_row, counts, rank);
    scanA<<<NSCAN, 256, 0, stream>>>(counts, bsum);
    scanC<<<NSCAN, 256, 0, stream>>>(counts, rpf, bsum);
    fill_k<<<eg_grid, 256, 0, stream>>>(edge_row, edge_col, edge_val, rpf, rank, edges);

    dim3 lay_grid((NE + NT - 1) / NT, 2);   // 782 x 2 relation-halves
    layer_k<false><<<lay_grid, 256, 0, stream>>>(embA,  Tf, rpf, edges, Dacc0);
    layer_k<true ><<<lay_grid, 256, 0, stream>>>(Dacc0, Tf, rpf, edges, Dacc1);
    final_k<<<NE / 8, 256, 0, stream>>>(Dacc1, out);
}